// Round 1
// baseline (613.463 us; speedup 1.0000x reference)
//
#include <hip/hip_runtime.h>
#include <hip/hip_bf16.h>
#include <stdint.h>
#include <stddef.h>

#define IN_F   4096
#define OUT_F  4096
#define RANK   16
#define GROUP  128
#define M_TOT  8192   // 8 * 1024
#define BM     128
#define BN     128
#define BK     32

typedef __bf16 bf16_t;
typedef __bf16 bf16x4 __attribute__((ext_vector_type(4)));
typedef __bf16 bf16x8 __attribute__((ext_vector_type(8)));
typedef float  f32x4  __attribute__((ext_vector_type(4)));

// ---------------------------------------------------------------------------
// async global -> LDS, 16B per lane. LDS dest is wave-uniform base + lane*16,
// so LDS layout must be contiguous in lane order (no padding).
// ---------------------------------------------------------------------------
__device__ static inline void load_lds16(const void* g, void* l) {
  __builtin_amdgcn_global_load_lds(
      (const __attribute__((address_space(1))) unsigned int*)g,
      (__attribute__((address_space(3))) unsigned int*)l,
      16, 0, 0);
}

// ---------------------------------------------------------------------------
// Kernel 1: w_q = fake-quant(w0 + lora_b @ lora_a), output bf16 [OUT_F][IN_F]
// Quantization math in exact fp32 to match the reference rounding decisions.
// One block per output row o; 256 threads x 4 passes x float4.
// ---------------------------------------------------------------------------
__global__ void __launch_bounds__(256)
quant_kernel(const float* __restrict__ w0, const float* __restrict__ la,
             const float* __restrict__ lb, const float* __restrict__ qs,
             bf16_t* __restrict__ wq)
{
  const int o = blockIdx.x;
  __shared__ float lbr[RANK];
  if (threadIdx.x < RANK) lbr[threadIdx.x] = lb[o * RANK + threadIdx.x];
  __syncthreads();

  const size_t rowoff = (size_t)o * IN_F;
  #pragma unroll
  for (int pass = 0; pass < 4; ++pass) {
    const int i = pass * 1024 + threadIdx.x * 4;
    const float4 w = *(const float4*)(w0 + rowoff + i);
    float a0 = w.x, a1 = w.y, a2 = w.z, a3 = w.w;
    #pragma unroll
    for (int r = 0; r < RANK; ++r) {
      const float4 av = *(const float4*)(la + (size_t)r * IN_F + i);
      const float bv = lbr[r];
      a0 = fmaf(bv, av.x, a0);
      a1 = fmaf(bv, av.y, a1);
      a2 = fmaf(bv, av.z, a2);
      a3 = fmaf(bv, av.w, a3);
    }
    // group = (o*IN_F + i) / GROUP = o*32 + i/128 ; all 4 elems share a group
    const float s   = qs[o * (IN_F / GROUP) + (i >> 7)];
    const float inv = 1.0f / (s + 1e-9f);
    const float q0 = rintf(fminf(fmaxf(a0 * inv, -8.0f), 7.0f)) * s;
    const float q1 = rintf(fminf(fmaxf(a1 * inv, -8.0f), 7.0f)) * s;
    const float q2 = rintf(fminf(fmaxf(a2 * inv, -8.0f), 7.0f)) * s;
    const float q3 = rintf(fminf(fmaxf(a3 * inv, -8.0f), 7.0f)) * s;
    bf16x4 v;
    v[0] = (bf16_t)q0; v[1] = (bf16_t)q1; v[2] = (bf16_t)q2; v[3] = (bf16_t)q3;
    *(bf16x4*)(wq + rowoff + i) = v;
  }
}

// ---------------------------------------------------------------------------
// Kernel 2: x fp32 -> bf16 (RNE), vectorized 8 elems/thread
// ---------------------------------------------------------------------------
__global__ void __launch_bounds__(256)
castx_kernel(const float* __restrict__ x, bf16_t* __restrict__ xb)
{
  const size_t i = ((size_t)blockIdx.x * 256 + threadIdx.x) * 8;
  const float4 a = *(const float4*)(x + i);
  const float4 b = *(const float4*)(x + i + 4);
  bf16x8 v;
  v[0] = (bf16_t)a.x; v[1] = (bf16_t)a.y; v[2] = (bf16_t)a.z; v[3] = (bf16_t)a.w;
  v[4] = (bf16_t)b.x; v[5] = (bf16_t)b.y; v[6] = (bf16_t)b.z; v[7] = (bf16_t)b.w;
  *(bf16x8*)(xb + i) = v;
}

// ---------------------------------------------------------------------------
// Kernel 3: GEMM  C[m][n] = sum_k A[m][k] * Bw[n][k] + bias[n]
// m97 structure: 128x128 tile, BK=32, 4 waves (2x2), each wave 4x4 frags of
// 16x16x32 bf16 MFMA. global_load_lds width=16 staging, ds_read_b128 frags.
// ---------------------------------------------------------------------------
__global__ void __launch_bounds__(256)
gemm_kernel(const bf16_t* __restrict__ A, const bf16_t* __restrict__ Bw,
            const float* __restrict__ bias, float* __restrict__ C)
{
  __shared__ __align__(16) bf16_t lA[BM * BK];   // 8 KiB, row-major [128][32]
  __shared__ __align__(16) bf16_t lB[BN * BK];   // 8 KiB, row-major [128][32]

  const int tid  = threadIdx.x;
  const int lane = tid & 63;
  const int lr   = lane & 15;    // row-in-16 for frag loads / col for C
  const int quad = lane >> 4;    // 0..3
  const int wave = tid >> 6;     // 0..3

  const int m0 = blockIdx.y * BM;
  const int n0 = blockIdx.x * BN;

  // staging: chunk c = pass*256 + tid covers LDS bytes [c*16, c*16+16)
  // = tile row c/4, bf16 cols (c%4)*8.. ; matches global row/col below.
  const int srow = tid >> 2;        // 0..63 (pass adds +64)
  const int scol = (tid & 3) * 8;   // bf16 offset within row

  const bf16_t* gA0 = A  + (size_t)(m0 + srow) * IN_F + scol;
  const bf16_t* gA1 = gA0 + (size_t)64 * IN_F;
  const bf16_t* gB0 = Bw + (size_t)(n0 + srow) * IN_F + scol;
  const bf16_t* gB1 = gB0 + (size_t)64 * IN_F;

  char* dA0 = (char*)lA + tid * 16;
  char* dA1 = (char*)lA + (256 + tid) * 16;
  char* dB0 = (char*)lB + tid * 16;
  char* dB1 = (char*)lB + (256 + tid) * 16;

  const int mb = (wave & 1) * 64;   // wave's m-base within tile
  const int nb = (wave >> 1) * 64;  // wave's n-base within tile

  f32x4 acc[4][4];
  #pragma unroll
  for (int i = 0; i < 4; ++i)
    #pragma unroll
    for (int j = 0; j < 4; ++j)
      acc[i][j] = (f32x4){0.f, 0.f, 0.f, 0.f};

  for (int kt = 0; kt < IN_F; kt += BK) {
    load_lds16(gA0 + kt, dA0);
    load_lds16(gA1 + kt, dA1);
    load_lds16(gB0 + kt, dB0);
    load_lds16(gB1 + kt, dB1);
    __syncthreads();   // compiler drains vmcnt(0) before s_barrier -> LDS ready

    // A frag: A[m = lane&15][k = quad*8 + j]; B frag symmetric (K-major both)
    bf16x8 af[4], bfr[4];
    #pragma unroll
    for (int f = 0; f < 4; ++f)
      af[f]  = *(const bf16x8*)(lA + (mb + f * 16 + lr) * BK + quad * 8);
    #pragma unroll
    for (int f = 0; f < 4; ++f)
      bfr[f] = *(const bf16x8*)(lB + (nb + f * 16 + lr) * BK + quad * 8);

    #pragma unroll
    for (int fm = 0; fm < 4; ++fm)
      #pragma unroll
      for (int fn = 0; fn < 4; ++fn)
        acc[fm][fn] = __builtin_amdgcn_mfma_f32_16x16x32_bf16(
            af[fm], bfr[fn], acc[fm][fn], 0, 0, 0);

    __syncthreads();   // all waves done reading before next overwrite
  }

  // Epilogue: C/D layout col = lane&15, row = quad*4 + reg (m89-verified)
  #pragma unroll
  for (int fn = 0; fn < 4; ++fn) {
    const int gn = n0 + nb + fn * 16 + lr;
    const float bv = bias[gn];
    #pragma unroll
    for (int fm = 0; fm < 4; ++fm) {
      const int gm = m0 + mb + fm * 16 + quad * 4;
      #pragma unroll
      for (int r = 0; r < 4; ++r)
        C[(size_t)(gm + r) * OUT_F + gn] = acc[fm][fn][r] + bv;
    }
  }
}

// ---------------------------------------------------------------------------
extern "C" void kernel_launch(void* const* d_in, const int* in_sizes, int n_in,
                              void* d_out, int out_size, void* d_ws, size_t ws_size,
                              hipStream_t stream) {
  const float* x    = (const float*)d_in[0];  // [8,1024,4096]
  const float* w0   = (const float*)d_in[1];  // [4096,4096]
  const float* la   = (const float*)d_in[2];  // [16,4096]
  const float* lb   = (const float*)d_in[3];  // [4096,16]
  const float* qs   = (const float*)d_in[4];  // [131072]
  const float* bias = (const float*)d_in[5];  // [4096]
  float* out = (float*)d_out;                 // [8,1024,4096] fp32

  bf16_t* wq = (bf16_t*)d_ws;                                         // 32 MiB
  bf16_t* xb = (bf16_t*)((char*)d_ws + (size_t)OUT_F * IN_F * 2);     // 64 MiB

  quant_kernel<<<OUT_F, 256, 0, stream>>>(w0, la, lb, qs, wq);
  castx_kernel<<<(M_TOT * IN_F) / (256 * 8), 256, 0, stream>>>(x, xb);
  gemm_kernel<<<dim3(OUT_F / BN, M_TOT / BM), 256, 0, stream>>>(xb, wq, bias, out);
}

// Round 2
// 608.552 us; speedup vs baseline: 1.0081x; 1.0081x over previous
//
#include <hip/hip_runtime.h>
#include <hip/hip_bf16.h>
#include <stdint.h>
#include <stddef.h>

#define IN_F   4096
#define OUT_F  4096
#define RANK   16
#define GROUP  128
#define M_TOT  8192   // 8 * 1024
#define BM     128
#define BN     128
#define BK     32

typedef __bf16 bf16_t;
typedef __bf16 bf16x4 __attribute__((ext_vector_type(4)));
typedef __bf16 bf16x8 __attribute__((ext_vector_type(8)));
typedef float  f32x4  __attribute__((ext_vector_type(4)));

// ---------------------------------------------------------------------------
// async global -> LDS, 16B per lane. LDS dest is wave-uniform base + lane*16,
// so LDS layout must be contiguous in lane order (no padding).
// ---------------------------------------------------------------------------
__device__ static inline void load_lds16(const void* g, void* l) {
  __builtin_amdgcn_global_load_lds(
      (const __attribute__((address_space(1))) unsigned int*)g,
      (__attribute__((address_space(3))) unsigned int*)l,
      16, 0, 0);
}

// ---------------------------------------------------------------------------
// Kernel 1: w_q = fake-quant(w0 + lora_b @ lora_a), output bf16 [OUT_F][IN_F]
// v2: one float4 per thread, 2D grid (col-chunk, row). No pass loop -> only
// 17 float4 live (~90 VGPR), no spills (v1's 4x-unrolled pass loop spilled).
// Quantization math in exact fp32 to match the reference rounding decisions.
// ---------------------------------------------------------------------------
__global__ void __launch_bounds__(256)
quant_kernel(const float* __restrict__ w0, const float* __restrict__ la,
             const float* __restrict__ lb, const float* __restrict__ qs,
             bf16_t* __restrict__ wq)
{
  const int o = blockIdx.y;                            // output row
  const int i = blockIdx.x * 1024 + threadIdx.x * 4;   // column (x4)

  __shared__ float lbr[RANK];
  if (threadIdx.x < RANK) lbr[threadIdx.x] = lb[o * RANK + threadIdx.x];
  __syncthreads();

  const size_t off = (size_t)o * IN_F + i;
  const float4 w = *(const float4*)(w0 + off);
  float a0 = w.x, a1 = w.y, a2 = w.z, a3 = w.w;
  #pragma unroll
  for (int r = 0; r < RANK; ++r) {
    const float4 av = *(const float4*)(la + (size_t)r * IN_F + i);
    const float bv = lbr[r];
    a0 = fmaf(bv, av.x, a0);
    a1 = fmaf(bv, av.y, a1);
    a2 = fmaf(bv, av.z, a2);
    a3 = fmaf(bv, av.w, a3);
  }
  // group = (o*IN_F + i) / GROUP = o*32 + i/128 ; all 4 elems share one group
  const float s   = qs[o * (IN_F / GROUP) + (i >> 7)];
  const float inv = 1.0f / (s + 1e-9f);
  const float q0 = rintf(fminf(fmaxf(a0 * inv, -8.0f), 7.0f)) * s;
  const float q1 = rintf(fminf(fmaxf(a1 * inv, -8.0f), 7.0f)) * s;
  const float q2 = rintf(fminf(fmaxf(a2 * inv, -8.0f), 7.0f)) * s;
  const float q3 = rintf(fminf(fmaxf(a3 * inv, -8.0f), 7.0f)) * s;
  bf16x4 v;
  v[0] = (bf16_t)q0; v[1] = (bf16_t)q1; v[2] = (bf16_t)q2; v[3] = (bf16_t)q3;
  *(bf16x4*)(wq + off) = v;
}

// ---------------------------------------------------------------------------
// Kernel 2: x fp32 -> bf16 (RNE), vectorized 8 elems/thread
// ---------------------------------------------------------------------------
__global__ void __launch_bounds__(256)
castx_kernel(const float* __restrict__ x, bf16_t* __restrict__ xb)
{
  const size_t i = ((size_t)blockIdx.x * 256 + threadIdx.x) * 8;
  const float4 a = *(const float4*)(x + i);
  const float4 b = *(const float4*)(x + i + 4);
  bf16x8 v;
  v[0] = (bf16_t)a.x; v[1] = (bf16_t)a.y; v[2] = (bf16_t)a.z; v[3] = (bf16_t)a.w;
  v[4] = (bf16_t)b.x; v[5] = (bf16_t)b.y; v[6] = (bf16_t)b.z; v[7] = (bf16_t)b.w;
  *(bf16x8*)(xb + i) = v;
}

// ---------------------------------------------------------------------------
// Kernel 3: GEMM  C[m][n] = sum_k A[m][k] * Bw[n][k] + bias[n]
// m97 structure: 128x128 tile, BK=32, 4 waves (2x2), each wave 4x4 frags of
// 16x16x32 bf16 MFMA. global_load_lds width=16 staging, ds_read_b128 frags.
// ---------------------------------------------------------------------------
__global__ void __launch_bounds__(256)
gemm_kernel(const bf16_t* __restrict__ A, const bf16_t* __restrict__ Bw,
            const float* __restrict__ bias, float* __restrict__ C)
{
  __shared__ __align__(16) bf16_t lA[BM * BK];   // 8 KiB, row-major [128][32]
  __shared__ __align__(16) bf16_t lB[BN * BK];   // 8 KiB, row-major [128][32]

  const int tid  = threadIdx.x;
  const int lane = tid & 63;
  const int lr   = lane & 15;    // row-in-16 for frag loads / col for C
  const int quad = lane >> 4;    // 0..3
  const int wave = tid >> 6;     // 0..3

  const int m0 = blockIdx.y * BM;
  const int n0 = blockIdx.x * BN;

  // staging: chunk c = pass*256 + tid covers LDS bytes [c*16, c*16+16)
  // = tile row c/4, bf16 cols (c%4)*8.. ; matches global row/col below.
  const int srow = tid >> 2;        // 0..63 (pass adds +64)
  const int scol = (tid & 3) * 8;   // bf16 offset within row

  const bf16_t* gA0 = A  + (size_t)(m0 + srow) * IN_F + scol;
  const bf16_t* gA1 = gA0 + (size_t)64 * IN_F;
  const bf16_t* gB0 = Bw + (size_t)(n0 + srow) * IN_F + scol;
  const bf16_t* gB1 = gB0 + (size_t)64 * IN_F;

  char* dA0 = (char*)lA + tid * 16;
  char* dA1 = (char*)lA + (256 + tid) * 16;
  char* dB0 = (char*)lB + tid * 16;
  char* dB1 = (char*)lB + (256 + tid) * 16;

  const int mb = (wave & 1) * 64;   // wave's m-base within tile
  const int nb = (wave >> 1) * 64;  // wave's n-base within tile

  f32x4 acc[4][4];
  #pragma unroll
  for (int i = 0; i < 4; ++i)
    #pragma unroll
    for (int j = 0; j < 4; ++j)
      acc[i][j] = (f32x4){0.f, 0.f, 0.f, 0.f};

  for (int kt = 0; kt < IN_F; kt += BK) {
    load_lds16(gA0 + kt, dA0);
    load_lds16(gA1 + kt, dA1);
    load_lds16(gB0 + kt, dB0);
    load_lds16(gB1 + kt, dB1);
    __syncthreads();   // compiler drains vmcnt(0) before s_barrier -> LDS ready

    // A frag: A[m = lane&15][k = quad*8 + j]; B frag symmetric (K-major both)
    bf16x8 af[4], bfr[4];
    #pragma unroll
    for (int f = 0; f < 4; ++f)
      af[f]  = *(const bf16x8*)(lA + (mb + f * 16 + lr) * BK + quad * 8);
    #pragma unroll
    for (int f = 0; f < 4; ++f)
      bfr[f] = *(const bf16x8*)(lB + (nb + f * 16 + lr) * BK + quad * 8);

    #pragma unroll
    for (int fm = 0; fm < 4; ++fm)
      #pragma unroll
      for (int fn = 0; fn < 4; ++fn)
        acc[fm][fn] = __builtin_amdgcn_mfma_f32_16x16x32_bf16(
            af[fm], bfr[fn], acc[fm][fn], 0, 0, 0);

    __syncthreads();   // all waves done reading before next overwrite
  }

  // Epilogue: C/D layout col = lane&15, row = quad*4 + reg (m89-verified)
  #pragma unroll
  for (int fn = 0; fn < 4; ++fn) {
    const int gn = n0 + nb + fn * 16 + lr;
    const float bv = bias[gn];
    #pragma unroll
    for (int fm = 0; fm < 4; ++fm) {
      const int gm = m0 + mb + fm * 16 + quad * 4;
      #pragma unroll
      for (int r = 0; r < 4; ++r)
        C[(size_t)(gm + r) * OUT_F + gn] = acc[fm][fn][r] + bv;
    }
  }
}

// ---------------------------------------------------------------------------
extern "C" void kernel_launch(void* const* d_in, const int* in_sizes, int n_in,
                              void* d_out, int out_size, void* d_ws, size_t ws_size,
                              hipStream_t stream) {
  const float* x    = (const float*)d_in[0];  // [8,1024,4096]
  const float* w0   = (const float*)d_in[1];  // [4096,4096]
  const float* la   = (const float*)d_in[2];  // [16,4096]
  const float* lb   = (const float*)d_in[3];  // [4096,16]
  const float* qs   = (const float*)d_in[4];  // [131072]
  const float* bias = (const float*)d_in[5];  // [4096]
  float* out = (float*)d_out;                 // [8,1024,4096] fp32

  bf16_t* wq = (bf16_t*)d_ws;                                         // 32 MiB
  bf16_t* xb = (bf16_t*)((char*)d_ws + (size_t)OUT_F * IN_F * 2);     // 64 MiB

  quant_kernel<<<dim3(IN_F / 1024, OUT_F), 256, 0, stream>>>(w0, la, lb, qs, wq);
  castx_kernel<<<(M_TOT * IN_F) / (256 * 8), 256, 0, stream>>>(x, xb);
  gemm_kernel<<<dim3(OUT_F / BN, M_TOT / BM), 256, 0, stream>>>(xb, wq, bias, out);
}

// Round 3
// 604.035 us; speedup vs baseline: 1.0156x; 1.0075x over previous
//
#include <hip/hip_runtime.h>
#include <hip/hip_bf16.h>
#include <stdint.h>
#include <stddef.h>

#define IN_F   4096
#define OUT_F  4096
#define RANK   16
#define GROUP  128
#define M_TOT  8192   // 8 * 1024
#define BM     128
#define BN     128
#define BK     32
#define NIT    (IN_F / BK)

typedef __bf16 bf16_t;
typedef __bf16 bf16x4 __attribute__((ext_vector_type(4)));
typedef __bf16 bf16x8 __attribute__((ext_vector_type(8)));
typedef float  f32x4  __attribute__((ext_vector_type(4)));

// ---------------------------------------------------------------------------
// async global -> LDS, 16B per lane. LDS dest is wave-uniform base + lane*16,
// so LDS layout must be contiguous in lane order (no padding).
// ---------------------------------------------------------------------------
__device__ static inline void load_lds16(const void* g, void* l) {
  __builtin_amdgcn_global_load_lds(
      (const __attribute__((address_space(1))) unsigned int*)g,
      (__attribute__((address_space(3))) unsigned int*)l,
      16, 0, 0);
}

// ---------------------------------------------------------------------------
// Kernel 1: w_q = fake-quant(w0 + lora_b @ lora_a), output bf16 [OUT_F][IN_F]
// One float4 per thread, 2D grid. Quantization math in exact fp32 to match
// the reference rounding decisions; only the final w_q is cast to bf16.
// ---------------------------------------------------------------------------
__global__ void __launch_bounds__(256)
quant_kernel(const float* __restrict__ w0, const float* __restrict__ la,
             const float* __restrict__ lb, const float* __restrict__ qs,
             bf16_t* __restrict__ wq)
{
  const int o = blockIdx.y;                            // output row
  const int i = blockIdx.x * 1024 + threadIdx.x * 4;   // column (x4)

  __shared__ float lbr[RANK];
  if (threadIdx.x < RANK) lbr[threadIdx.x] = lb[o * RANK + threadIdx.x];
  __syncthreads();

  const size_t off = (size_t)o * IN_F + i;
  const float4 w = *(const float4*)(w0 + off);
  float a0 = w.x, a1 = w.y, a2 = w.z, a3 = w.w;
  #pragma unroll
  for (int r = 0; r < RANK; ++r) {
    const float4 av = *(const float4*)(la + (size_t)r * IN_F + i);
    const float bv = lbr[r];
    a0 = fmaf(bv, av.x, a0);
    a1 = fmaf(bv, av.y, a1);
    a2 = fmaf(bv, av.z, a2);
    a3 = fmaf(bv, av.w, a3);
  }
  const float s   = qs[o * (IN_F / GROUP) + (i >> 7)];
  const float inv = 1.0f / (s + 1e-9f);
  const float q0 = rintf(fminf(fmaxf(a0 * inv, -8.0f), 7.0f)) * s;
  const float q1 = rintf(fminf(fmaxf(a1 * inv, -8.0f), 7.0f)) * s;
  const float q2 = rintf(fminf(fmaxf(a2 * inv, -8.0f), 7.0f)) * s;
  const float q3 = rintf(fminf(fmaxf(a3 * inv, -8.0f), 7.0f)) * s;
  bf16x4 v;
  v[0] = (bf16_t)q0; v[1] = (bf16_t)q1; v[2] = (bf16_t)q2; v[3] = (bf16_t)q3;
  *(bf16x4*)(wq + off) = v;
}

// ---------------------------------------------------------------------------
// Kernel 2: x fp32 -> bf16 (RNE), vectorized 8 elems/thread
// ---------------------------------------------------------------------------
__global__ void __launch_bounds__(256)
castx_kernel(const float* __restrict__ x, bf16_t* __restrict__ xb)
{
  const size_t i = ((size_t)blockIdx.x * 256 + threadIdx.x) * 8;
  const float4 a = *(const float4*)(x + i);
  const float4 b = *(const float4*)(x + i + 4);
  bf16x8 v;
  v[0] = (bf16_t)a.x; v[1] = (bf16_t)a.y; v[2] = (bf16_t)a.z; v[3] = (bf16_t)a.w;
  v[4] = (bf16_t)b.x; v[5] = (bf16_t)b.y; v[6] = (bf16_t)b.z; v[7] = (bf16_t)b.w;
  *(bf16x8*)(xb + i) = v;
}

// ---------------------------------------------------------------------------
// Kernel 3: GEMM  C[m][n] = sum_k A[m][k] * Bw[n][k] + bias[n]
// v3: double-buffered LDS, ONE barrier per K-iter. Loads for tile k+1 issue
// right after the barrier that publishes tile k, so the vmcnt(0) drain at the
// NEXT barrier waits on loads already one compute-iteration old.
// Safety: all waves' ds_reads of buf^1 (iter k-1) precede the barrier at iter
// k, which releases the loads into buf^1 — no WAR hazard, wave-uniform branch.
// ---------------------------------------------------------------------------
__global__ void __launch_bounds__(256, 3)
gemm_kernel(const bf16_t* __restrict__ A, const bf16_t* __restrict__ Bw,
            const float* __restrict__ bias, float* __restrict__ C)
{
  __shared__ __align__(16) bf16_t lA[2][BM * BK];   // 2 x 8 KiB
  __shared__ __align__(16) bf16_t lB[2][BN * BK];   // 2 x 8 KiB

  const int tid  = threadIdx.x;
  const int lane = tid & 63;
  const int lr   = lane & 15;    // row-in-16 for frag loads / col for C
  const int quad = lane >> 4;    // 0..3
  const int wave = tid >> 6;     // 0..3

  const int m0 = blockIdx.y * BM;
  const int n0 = blockIdx.x * BN;

  // staging: chunk c = pass*256 + tid covers LDS bytes [c*16, c*16+16)
  const int srow = tid >> 2;        // 0..63 (second half adds +64)
  const int scol = (tid & 3) * 8;   // bf16 offset within row

  const bf16_t* gA0 = A  + (size_t)(m0 + srow) * IN_F + scol;
  const bf16_t* gA1 = gA0 + (size_t)64 * IN_F;
  const bf16_t* gB0 = Bw + (size_t)(n0 + srow) * IN_F + scol;
  const bf16_t* gB1 = gB0 + (size_t)64 * IN_F;

  const int mb = (wave & 1) * 64;   // wave's m-base within tile
  const int nb = (wave >> 1) * 64;  // wave's n-base within tile

  f32x4 acc[4][4];
  #pragma unroll
  for (int i = 0; i < 4; ++i)
    #pragma unroll
    for (int j = 0; j < 4; ++j)
      acc[i][j] = (f32x4){0.f, 0.f, 0.f, 0.f};

  // prime buffer 0 with tile 0
  {
    char* dA = (char*)lA[0] + tid * 16;
    char* dB = (char*)lB[0] + tid * 16;
    load_lds16(gA0, dA);
    load_lds16(gA1, dA + 4096);
    load_lds16(gB0, dB);
    load_lds16(gB1, dB + 4096);
  }

  int buf = 0;
  for (int it = 0; it < NIT; ++it) {
    __syncthreads();   // publishes tile `it` in `buf`; all reads of buf^1 done

    if (it + 1 < NIT) {                   // wave-uniform
      const int kt = (it + 1) * BK;
      char* dA = (char*)lA[buf ^ 1] + tid * 16;
      char* dB = (char*)lB[buf ^ 1] + tid * 16;
      load_lds16(gA0 + kt, dA);
      load_lds16(gA1 + kt, dA + 4096);
      load_lds16(gB0 + kt, dB);
      load_lds16(gB1 + kt, dB + 4096);
    }

    // A frag: A[m = lane&15][k = quad*8 + j]; B frag symmetric (K-major both)
    const bf16_t* sA = lA[buf];
    const bf16_t* sB = lB[buf];
    bf16x8 af[4], bfr[4];
    #pragma unroll
    for (int f = 0; f < 4; ++f)
      af[f]  = *(const bf16x8*)(sA + (mb + f * 16 + lr) * BK + quad * 8);
    #pragma unroll
    for (int f = 0; f < 4; ++f)
      bfr[f] = *(const bf16x8*)(sB + (nb + f * 16 + lr) * BK + quad * 8);

    #pragma unroll
    for (int fm = 0; fm < 4; ++fm)
      #pragma unroll
      for (int fn = 0; fn < 4; ++fn)
        acc[fm][fn] = __builtin_amdgcn_mfma_f32_16x16x32_bf16(
            af[fm], bfr[fn], acc[fm][fn], 0, 0, 0);

    buf ^= 1;
  }

  // Epilogue: C/D layout col = lane&15, row = quad*4 + reg (m89-verified)
  #pragma unroll
  for (int fn = 0; fn < 4; ++fn) {
    const int gn = n0 + nb + fn * 16 + lr;
    const float bv = bias[gn];
    #pragma unroll
    for (int fm = 0; fm < 4; ++fm) {
      const int gm = m0 + mb + fm * 16 + quad * 4;
      #pragma unroll
      for (int r = 0; r < 4; ++r)
        C[(size_t)(gm + r) * OUT_F + gn] = acc[fm][fn][r] + bv;
    }
  }
}

// ---------------------------------------------------------------------------
extern "C" void kernel_launch(void* const* d_in, const int* in_sizes, int n_in,
                              void* d_out, int out_size, void* d_ws, size_t ws_size,
                              hipStream_t stream) {
  const float* x    = (const float*)d_in[0];  // [8,1024,4096]
  const float* w0   = (const float*)d_in[1];  // [4096,4096]
  const float* la   = (const float*)d_in[2];  // [16,4096]
  const float* lb   = (const float*)d_in[3];  // [4096,16]
  const float* qs   = (const float*)d_in[4];  // [131072]
  const float* bias = (const float*)d_in[5];  // [4096]
  float* out = (float*)d_out;                 // [8,1024,4096] fp32

  bf16_t* wq = (bf16_t*)d_ws;                                         // 32 MiB
  bf16_t* xb = (bf16_t*)((char*)d_ws + (size_t)OUT_F * IN_F * 2);     // 64 MiB

  quant_kernel<<<dim3(IN_F / 1024, OUT_F), 256, 0, stream>>>(w0, la, lb, qs, wq);
  castx_kernel<<<(M_TOT * IN_F) / (256 * 8), 256, 0, stream>>>(x, xb);
  gemm_kernel<<<dim3(OUT_F / BN, M_TOT / BM), 256, 0, stream>>>(xb, wq, bias, out);
}